// Round 1
// baseline (691.550 us; speedup 1.0000x reference)
//
#include <hip/hip_runtime.h>
#include <hip/hip_bf16.h>
#include <math.h>

// Problem constants
#define NB 8
#define NS 512
#define NH 768
#define NL 8192

typedef __attribute__((ext_vector_type(8))) __bf16 bf16x8;
typedef __attribute__((ext_vector_type(4))) float f32x4;

static __device__ __forceinline__ f32x4 mfma_bf16(bf16x8 a, bf16x8 b, f32x4 c) {
  return __builtin_amdgcn_mfma_f32_16x16x32_bf16(a, b, c, 0, 0, 0);
}

// load 8 consecutive fp32 and round-to-nearest to bf16x8
static __device__ __forceinline__ bf16x8 load_cvt8(const float* __restrict__ p) {
  f32x4 u0 = *(const f32x4*)p;
  f32x4 u1 = *(const f32x4*)(p + 4);
  bf16x8 r;
  r[0] = (__bf16)u0[0]; r[1] = (__bf16)u0[1]; r[2] = (__bf16)u0[2]; r[3] = (__bf16)u0[3];
  r[4] = (__bf16)u1[0]; r[5] = (__bf16)u1[1]; r[6] = (__bf16)u1[2]; r[7] = (__bf16)u1[3];
  return r;
}

// ---------------------------------------------------------------------------
// Mask dtype detection. jnp.bool_ may arrive as int8 (raw bool), int32
// (harness upcast of "integer"), or float32. We probe bytes [0,4096), which is
// in-bounds under every interpretation (int8 buffer = 4KB exactly).
//  - any dword == 0x3F800000 -> float32 (bool bytes are only 0/1, can't form it)
//  - else any nonzero byte at offset%4!=0 -> int8 (prob ~0 of false negative)
//  - else -> int32
// flag: 0=int32, 1=int8, 2=float32
// ---------------------------------------------------------------------------
__global__ void detect_mask_kernel(const unsigned char* __restrict__ m,
                                   int* __restrict__ flag) {
  __shared__ int s_i8, s_f32;
  if (threadIdx.x == 0) { s_i8 = 0; s_f32 = 0; }
  __syncthreads();
  const unsigned int* md = (const unsigned int*)m;
  int li8 = 0, lf = 0;
  for (int i = threadIdx.x; i < 1024; i += blockDim.x) {
    unsigned int d = md[i];
    if (d == 0x3F800000u) lf = 1;
    if (d & 0xFFFFFF00u) li8 = 1;  // nonzero beyond byte0 of the dword
  }
  if (li8) atomicOr(&s_i8, 1);
  if (lf) atomicOr(&s_f32, 1);
  __syncthreads();
  if (threadIdx.x == 0) *flag = s_f32 ? 2 : (s_i8 ? 1 : 0);
}

__global__ void expand_mask_kernel(const void* __restrict__ m,
                                   const int* __restrict__ flag,
                                   float* __restrict__ mbias) {
  int i = blockIdx.x * blockDim.x + threadIdx.x;  // 0..4095
  int f = *flag;
  int v;
  if (f == 1)      v = (((const unsigned char*)m)[i] != 0);
  else if (f == 2) v = (((const float*)m)[i] != 0.0f);
  else             v = (((const int*)m)[i] != 0);
  mbias[i] = v ? 0.0f : -INFINITY;
}

// ---------------------------------------------------------------------------
// K_bf16[rs][o] = bf16( sum_h X[rs][h] * W[o][h] ),  rs = b*512+s flattened.
// NT layout: both operands K(=h)-major. 4 waves, 64x64 tile, wave 32x32.
// ---------------------------------------------------------------------------
__global__ __launch_bounds__(256) void proj_kernel(const float* __restrict__ X,
                                                   const float* __restrict__ W,
                                                   __bf16* __restrict__ Kout) {
  const int tid = threadIdx.x;
  const int lane = tid & 63, wid = tid >> 6;
  const int c = lane & 15, g = lane >> 4;
  const int wm = wid >> 1, wn = wid & 1;
  const int m0 = blockIdx.x * 64 + wm * 32;
  const int n0 = blockIdx.y * 64 + wn * 32;
  f32x4 acc[2][2] = {};
  const float* Xp = X + (size_t)(m0 + c) * NH + g * 8;
  const float* Wp = W + (size_t)(n0 + c) * NH + g * 8;
  for (int k = 0; k < NH; k += 32) {
    bf16x8 a0 = load_cvt8(Xp + k);
    bf16x8 a1 = load_cvt8(Xp + 16 * NH + k);
    bf16x8 b0 = load_cvt8(Wp + k);
    bf16x8 b1 = load_cvt8(Wp + 16 * NH + k);
    acc[0][0] = mfma_bf16(a0, b0, acc[0][0]);
    acc[0][1] = mfma_bf16(a0, b1, acc[0][1]);
    acc[1][0] = mfma_bf16(a1, b0, acc[1][0]);
    acc[1][1] = mfma_bf16(a1, b1, acc[1][1]);
  }
#pragma unroll
  for (int fm = 0; fm < 2; ++fm)
#pragma unroll
    for (int fn = 0; fn < 2; ++fn)
#pragma unroll
      for (int r = 0; r < 4; ++r) {
        int row = m0 + fm * 16 + g * 4 + r;
        int col = n0 + fn * 16 + c;
        Kout[(size_t)row * NH + col] = (__bf16)acc[fm][fn][r];
      }
}

// XT_bf16[b][h][s] = bf16(X[b][s][h]) — padded-LDS tile transpose
__global__ __launch_bounds__(256) void transpose_kernel(const float* __restrict__ X,
                                                        __bf16* __restrict__ XT) {
  __shared__ float t[64][65];
  const int b = blockIdx.z, s0 = blockIdx.y * 64, h0 = blockIdx.x * 64;
  const int j = threadIdx.x & 63, i0 = threadIdx.x >> 6;
  const float* Xb = X + ((size_t)b * NS + s0) * NH + h0;
#pragma unroll
  for (int i = i0; i < 64; i += 4) t[i][j] = Xb[(size_t)i * NH + j];
  __syncthreads();
  __bf16* XTb = XT + ((size_t)b * NH + h0) * NS + s0;
  const int si = threadIdx.x & 63, j0 = threadIdx.x >> 6;
#pragma unroll
  for (int jj = j0; jj < 64; jj += 4)
    XTb[(size_t)jj * NS + si] = (__bf16)t[si][jj];
}

// E_bf16 = bf16(label_embedding), elementwise, 8 elems/thread
__global__ __launch_bounds__(256) void cast_kernel(const float* __restrict__ E,
                                                   __bf16* __restrict__ Eb) {
  size_t idx = ((size_t)blockIdx.x * 256 + threadIdx.x) * 8;
  bf16x8 v = load_cvt8(E + idx);
  *(bf16x8*)(Eb + idx) = v;
}

// ---------------------------------------------------------------------------
// Fused: per (b, 64-label tile): scores=E@K^T -> masked softmax -> P@X.
// 8 waves (512 thr). Phase1 waves 2(M)x4(N): wave 32x128, acc 2x8 frags.
// Phase3 waves 2(M)x4(N): wave 32x192, acc 2x12 frags.
// P kept in LDS as bf16 with XOR swizzle (col ^= (row&7)<<3) so phase-3
// ds_read_b128 A-frag reads are bank-conflict-free.
// ---------------------------------------------------------------------------
__global__ __launch_bounds__(512) void label_attn_kernel(
    const __bf16* __restrict__ Ebf,   // [NL, NH]
    const __bf16* __restrict__ Kbf,   // [NB, NS, NH]
    const __bf16* __restrict__ XTbf,  // [NB, NH, NS]
    const float* __restrict__ mbias,  // [NB, NS] 0 or -inf
    float* __restrict__ Out) {        // [NB, NL, NH]
  const int tid = threadIdx.x;
  const int lane = tid & 63, wid = tid >> 6;
  const int c = lane & 15, g = lane >> 4;
  const int wm = wid >> 2, wn = wid & 3;
  const int b = blockIdx.y;
  const int R0 = blockIdx.x * 64;

  __shared__ alignas(16) __bf16 Plds[64 * 512];
  __shared__ float redM[4][64];
  __shared__ float redS[4][64];

  // ---- Phase 1: scores[64 x 512] ----
  f32x4 acc[2][8];
#pragma unroll
  for (int i = 0; i < 2; ++i)
#pragma unroll
    for (int j = 0; j < 8; ++j) acc[i][j] = (f32x4){0.f, 0.f, 0.f, 0.f};

  const __bf16* Ea = Ebf + (size_t)(R0 + wm * 32 + c) * NH + g * 8;
  const __bf16* Kb = Kbf + ((size_t)b * NS + wn * 128 + c) * NH + g * 8;

  float bias[8];
#pragma unroll
  for (int fn = 0; fn < 8; ++fn) bias[fn] = mbias[b * NS + wn * 128 + fn * 16 + c];

  for (int k = 0; k < NH; k += 32) {
    bf16x8 a0 = *(const bf16x8*)(Ea + k);
    bf16x8 a1 = *(const bf16x8*)(Ea + 16 * NH + k);
#pragma unroll
    for (int fn = 0; fn < 8; ++fn) {
      bf16x8 bb = *(const bf16x8*)(Kb + (size_t)fn * 16 * NH + k);
      acc[0][fn] = mfma_bf16(a0, bb, acc[0][fn]);
      acc[1][fn] = mfma_bf16(a1, bb, acc[1][fn]);
    }
  }

  // ---- Phase 2: masked softmax over s ----
  float pmax[2][4];
#pragma unroll
  for (int fm = 0; fm < 2; ++fm)
#pragma unroll
    for (int r = 0; r < 4; ++r) {
      float v = -INFINITY;
#pragma unroll
      for (int fn = 0; fn < 8; ++fn) v = fmaxf(v, acc[fm][fn][r] + bias[fn]);
#pragma unroll
      for (int off = 1; off < 16; off <<= 1) v = fmaxf(v, __shfl_xor(v, off));
      pmax[fm][r] = v;
    }
  if (c == 0) {
#pragma unroll
    for (int fm = 0; fm < 2; ++fm)
#pragma unroll
      for (int r = 0; r < 4; ++r)
        redM[wn][wm * 32 + fm * 16 + g * 4 + r] = pmax[fm][r];
  }
  __syncthreads();
  float rmax[2][4];
#pragma unroll
  for (int fm = 0; fm < 2; ++fm)
#pragma unroll
    for (int r = 0; r < 4; ++r) {
      int row = wm * 32 + fm * 16 + g * 4 + r;
      rmax[fm][r] = fmaxf(fmaxf(redM[0][row], redM[1][row]),
                          fmaxf(redM[2][row], redM[3][row]));
    }

  float psum[2][4] = {{0.f, 0.f, 0.f, 0.f}, {0.f, 0.f, 0.f, 0.f}};
#pragma unroll
  for (int fm = 0; fm < 2; ++fm)
#pragma unroll
    for (int fn = 0; fn < 8; ++fn) {
      int col = wn * 128 + fn * 16 + c;
#pragma unroll
      for (int r = 0; r < 4; ++r) {
        int row = wm * 32 + fm * 16 + g * 4 + r;
        float p = __expf(acc[fm][fn][r] + bias[fn] - rmax[fm][r]);
        psum[fm][r] += p;
        Plds[row * 512 + (col ^ ((row & 7) << 3))] = (__bf16)p;
      }
    }
#pragma unroll
  for (int fm = 0; fm < 2; ++fm)
#pragma unroll
    for (int r = 0; r < 4; ++r) {
      float v = psum[fm][r];
#pragma unroll
      for (int off = 1; off < 16; off <<= 1) v += __shfl_xor(v, off);
      psum[fm][r] = v;
    }
  if (c == 0) {
#pragma unroll
    for (int fm = 0; fm < 2; ++fm)
#pragma unroll
      for (int r = 0; r < 4; ++r)
        redS[wn][wm * 32 + fm * 16 + g * 4 + r] = psum[fm][r];
  }
  __syncthreads();  // covers redS AND all Plds writes
  float inv[2][4];
#pragma unroll
  for (int fm = 0; fm < 2; ++fm)
#pragma unroll
    for (int r = 0; r < 4; ++r) {
      int row = wm * 32 + fm * 16 + g * 4 + r;
      float s = redS[0][row] + redS[1][row] + redS[2][row] + redS[3][row];
      inv[fm][r] = 1.0f / s;
    }

  // ---- Phase 3: Out_tile[64 x 768] = P @ X_b (K=s=512) ----
  f32x4 acc2[2][12];
#pragma unroll
  for (int i = 0; i < 2; ++i)
#pragma unroll
    for (int j = 0; j < 12; ++j) acc2[i][j] = (f32x4){0.f, 0.f, 0.f, 0.f};

  const __bf16* XTb = XTbf + ((size_t)b * NH + wn * 192 + c) * NS + g * 8;
  const int r0 = wm * 32 + c;
  const int r1 = r0 + 16;
  for (int ks = 0; ks < NS; ks += 32) {
    int kk = ks + g * 8;
    bf16x8 a0 = *(const bf16x8*)&Plds[r0 * 512 + (kk ^ ((r0 & 7) << 3))];
    bf16x8 a1 = *(const bf16x8*)&Plds[r1 * 512 + (kk ^ ((r1 & 7) << 3))];
#pragma unroll
    for (int fn = 0; fn < 12; ++fn) {
      bf16x8 bb = *(const bf16x8*)(XTb + (size_t)fn * 16 * NS + ks);
      acc2[0][fn] = mfma_bf16(a0, bb, acc2[0][fn]);
      acc2[1][fn] = mfma_bf16(a1, bb, acc2[1][fn]);
    }
  }

  float* Ob = Out + ((size_t)b * NL + R0) * NH;
#pragma unroll
  for (int fm = 0; fm < 2; ++fm)
#pragma unroll
    for (int r = 0; r < 4; ++r) {
      int row = wm * 32 + fm * 16 + g * 4 + r;
      float sc = inv[fm][r];
#pragma unroll
      for (int fn = 0; fn < 12; ++fn) {
        int h = wn * 192 + fn * 16 + c;
        Ob[(size_t)row * NH + h] = acc2[fm][fn][r] * sc;
      }
    }
}

// ---------------------------------------------------------------------------
extern "C" void kernel_launch(void* const* d_in, const int* in_sizes, int n_in,
                              void* d_out, int out_size, void* d_ws, size_t ws_size,
                              hipStream_t stream) {
  const float* X = (const float*)d_in[0];        // [8,512,768]
  const void* masks = d_in[1];                   // [8,1,512] bool (dtype probed)
  const float* E = (const float*)d_in[2];        // [8192,768]
  const float* W = (const float*)d_in[3];        // [768,768]
  float* Out = (float*)d_out;                    // [8,8192,768]

  // workspace layout (≈25.2 MB total)
  char* ws = (char*)d_ws;
  __bf16* Kbf = (__bf16*)ws;                              // 6,291,456 B
  __bf16* XTbf = (__bf16*)(ws + 6291456);                 // 6,291,456 B
  __bf16* Ebf = (__bf16*)(ws + 12582912);                 // 12,582,912 B
  float* mbias = (float*)(ws + 25165824);                 // 16,384 B
  int* flag = (int*)(ws + 25182208);                      // 4 B

  detect_mask_kernel<<<1, 256, 0, stream>>>((const unsigned char*)masks, flag);
  expand_mask_kernel<<<16, 256, 0, stream>>>(masks, flag, mbias);
  proj_kernel<<<dim3(64, 12), 256, 0, stream>>>(X, W, Kbf);
  transpose_kernel<<<dim3(12, 8, 8), 256, 0, stream>>>(X, XTbf);
  cast_kernel<<<3072, 256, 0, stream>>>(E, Ebf);
  label_attn_kernel<<<dim3(128, 8), 512, 0, stream>>>(Ebf, Kbf, XTbf, mbias, Out);
}

// Round 2
// 389.020 us; speedup vs baseline: 1.7777x; 1.7777x over previous
//
#include <hip/hip_runtime.h>
#include <hip/hip_bf16.h>
#include <math.h>

// Problem constants
#define NB 8
#define NS 512
#define NH 768
#define NL 8192

typedef __attribute__((ext_vector_type(8))) __bf16 bf16x8;
typedef __attribute__((ext_vector_type(4))) float f32x4;

static __device__ __forceinline__ f32x4 mfma_bf16(bf16x8 a, bf16x8 b, f32x4 c) {
  return __builtin_amdgcn_mfma_f32_16x16x32_bf16(a, b, c, 0, 0, 0);
}

// async global->LDS, 16B per lane. LDS dest = wave-uniform base + lane*16.
static __device__ __forceinline__ void llds16(const void* g, void* l) {
  __builtin_amdgcn_global_load_lds(
      (const __attribute__((address_space(1))) unsigned int*)g,
      (__attribute__((address_space(3))) unsigned int*)l, 16, 0, 0);
}

// load 8 consecutive fp32 and round-to-nearest to bf16x8
static __device__ __forceinline__ bf16x8 load_cvt8(const float* __restrict__ p) {
  f32x4 u0 = *(const f32x4*)p;
  f32x4 u1 = *(const f32x4*)(p + 4);
  bf16x8 r;
  r[0] = (__bf16)u0[0]; r[1] = (__bf16)u0[1]; r[2] = (__bf16)u0[2]; r[3] = (__bf16)u0[3];
  r[4] = (__bf16)u1[0]; r[5] = (__bf16)u1[1]; r[6] = (__bf16)u1[2]; r[7] = (__bf16)u1[3];
  return r;
}

// ---------------------------------------------------------------------------
// Mask dtype detection (unchanged from round 1 — verified working).
// flag: 0=int32, 1=int8, 2=float32
// ---------------------------------------------------------------------------
__global__ void detect_mask_kernel(const unsigned char* __restrict__ m,
                                   int* __restrict__ flag) {
  __shared__ int s_i8, s_f32;
  if (threadIdx.x == 0) { s_i8 = 0; s_f32 = 0; }
  __syncthreads();
  const unsigned int* md = (const unsigned int*)m;
  int li8 = 0, lf = 0;
  for (int i = threadIdx.x; i < 1024; i += blockDim.x) {
    unsigned int d = md[i];
    if (d == 0x3F800000u) lf = 1;
    if (d & 0xFFFFFF00u) li8 = 1;
  }
  if (li8) atomicOr(&s_i8, 1);
  if (lf) atomicOr(&s_f32, 1);
  __syncthreads();
  if (threadIdx.x == 0) *flag = s_f32 ? 2 : (s_i8 ? 1 : 0);
}

__global__ void expand_mask_kernel(const void* __restrict__ m,
                                   const int* __restrict__ flag,
                                   float* __restrict__ mbias) {
  int i = blockIdx.x * blockDim.x + threadIdx.x;  // 0..4095
  int f = *flag;
  int v;
  if (f == 1)      v = (((const unsigned char*)m)[i] != 0);
  else if (f == 2) v = (((const float*)m)[i] != 0.0f);
  else             v = (((const int*)m)[i] != 0);
  mbias[i] = v ? 0.0f : -INFINITY;
}

// generic f32 -> bf16 cast, 8 elems/thread, n must be multiple of 2048
__global__ __launch_bounds__(256) void cast_kernel(const float* __restrict__ src,
                                                   __bf16* __restrict__ dst) {
  size_t idx = ((size_t)blockIdx.x * 256 + threadIdx.x) * 8;
  bf16x8 v = load_cvt8(src + idx);
  *(bf16x8*)(dst + idx) = v;
}

// XT_bf16[b][h][s] = bf16(X[b][s][h]) — padded-LDS tile transpose (round-1, verified)
__global__ __launch_bounds__(256) void transpose_kernel(const float* __restrict__ X,
                                                        __bf16* __restrict__ XT) {
  __shared__ float t[64][65];
  const int b = blockIdx.z, s0 = blockIdx.y * 64, h0 = blockIdx.x * 64;
  const int j = threadIdx.x & 63, i0 = threadIdx.x >> 6;
  const float* Xb = X + ((size_t)b * NS + s0) * NH + h0;
#pragma unroll
  for (int i = i0; i < 64; i += 4) t[i][j] = Xb[(size_t)i * NH + j];
  __syncthreads();
  __bf16* XTb = XT + ((size_t)b * NH + h0) * NS + s0;
  const int si = threadIdx.x & 63, j0 = threadIdx.x >> 6;
#pragma unroll
  for (int jj = j0; jj < 64; jj += 4)
    XTb[(size_t)jj * NS + si] = (__bf16)t[si][jj];
}

// ---------------------------------------------------------------------------
// m97-style staged GEMM: proj. Kout[m][n] = sum_k Xbf[m][k]*Wbf[n][k].
// M=4096, N=768, K=768. 128x128 tile, 4 waves (2x2), wave 64x64, BK=32.
// ---------------------------------------------------------------------------
__global__ __launch_bounds__(256, 3) void proj_staged_kernel(
    const __bf16* __restrict__ Xbf, const __bf16* __restrict__ Wbf,
    __bf16* __restrict__ Kout) {
  const int tid = threadIdx.x, lane = tid & 63, wid = tid >> 6;
  const int c = lane & 15, g = lane >> 4;
  const int wm = wid >> 1, wn = wid & 1;
  const int m0 = blockIdx.x * 128;
  const int n0 = blockIdx.y * 128;
  __shared__ __align__(16) unsigned char smem[2][16384];

  f32x4 acc[4][4];
#pragma unroll
  for (int i = 0; i < 4; ++i)
#pragma unroll
    for (int j = 0; j < 4; ++j) acc[i][j] = (f32x4){0.f, 0.f, 0.f, 0.f};

  auto stage = [&](int buf, int k0) {
#pragma unroll
    for (int it = 0; it < 2; ++it) {
      int ch = it * 4 + wid;              // 0..7
      int idx = ch * 64 + lane;           // 0..511
      int row = idx >> 2, slot = idx & 3;
      llds16(Xbf + (size_t)(m0 + row) * NH + k0 + slot * 8, &smem[buf][ch * 1024]);
      llds16(Wbf + (size_t)(n0 + row) * NH + k0 + slot * 8, &smem[buf][8192 + ch * 1024]);
    }
  };

  stage(0, 0);
  __syncthreads();
  int cur = 0;
  for (int t = 0; t < 24; ++t) {
    if (t < 23) stage(cur ^ 1, (t + 1) * 32);
    const unsigned char* A = smem[cur];
    const unsigned char* B = smem[cur] + 8192;
    bf16x8 af[4], bfr[4];
#pragma unroll
    for (int fm = 0; fm < 4; ++fm)
      af[fm] = *(const bf16x8*)(A + (wm * 64 + fm * 16 + c) * 64 + g * 16);
#pragma unroll
    for (int fn = 0; fn < 4; ++fn)
      bfr[fn] = *(const bf16x8*)(B + (wn * 64 + fn * 16 + c) * 64 + g * 16);
#pragma unroll
    for (int fm = 0; fm < 4; ++fm)
#pragma unroll
      for (int fn = 0; fn < 4; ++fn)
        acc[fm][fn] = mfma_bf16(af[fm], bfr[fn], acc[fm][fn]);
    __syncthreads();
    cur ^= 1;
  }
#pragma unroll
  for (int fm = 0; fm < 4; ++fm)
#pragma unroll
    for (int r = 0; r < 4; ++r) {
      int row = m0 + wm * 64 + fm * 16 + g * 4 + r;
#pragma unroll
      for (int fn = 0; fn < 4; ++fn)
        Kout[(size_t)row * NH + n0 + wn * 64 + fn * 16 + c] = (__bf16)acc[fm][fn][r];
    }
}

// ---------------------------------------------------------------------------
// K1: scores + softmax + normalized P (bf16) to ws.
// Block = 128 labels x 512 s (full row for softmax), K=768, BK=32.
// 8 waves (2M x 4N), wave 64x128: acc[4][8]. LDS dbuf 2x40KB.
// ---------------------------------------------------------------------------
__global__ __launch_bounds__(512, 2) void scores_kernel(
    const __bf16* __restrict__ Ebf,   // [NL, NH]
    const __bf16* __restrict__ Kbf,   // [NB*NS, NH]
    const float* __restrict__ mbias,  // [NB, NS]
    __bf16* __restrict__ Pws) {       // [NB*NL, NS]
  const int tid = threadIdx.x, lane = tid & 63, wid = tid >> 6;
  const int c = lane & 15, g = lane >> 4;
  const int wm = wid >> 2, wn = wid & 3;   // 2 x 4
  const int b = blockIdx.y;
  const int R0 = blockIdx.x * 128;
  __shared__ __align__(16) unsigned char smem[2][40960];
  const __bf16* Kb0 = Kbf + (size_t)b * NS * NH;

  f32x4 acc[4][8];
#pragma unroll
  for (int i = 0; i < 4; ++i)
#pragma unroll
    for (int j = 0; j < 8; ++j) acc[i][j] = (f32x4){0.f, 0.f, 0.f, 0.f};

  auto stage = [&](int buf, int k0) {
    // A: E-tile [128][32] = 8 chunks (one per wave)
    {
      int idx = wid * 64 + lane;
      int row = idx >> 2, slot = idx & 3;
      llds16(Ebf + (size_t)(R0 + row) * NH + k0 + slot * 8, &smem[buf][wid * 1024]);
    }
    // B: K-tile [512][32] = 32 chunks (4 per wave)
#pragma unroll
    for (int it = 0; it < 4; ++it) {
      int bc = it * 8 + wid;              // 0..31
      int idx = bc * 64 + lane;           // 0..2047
      int row = idx >> 2, slot = idx & 3;
      llds16(Kb0 + (size_t)row * NH + k0 + slot * 8, &smem[buf][8192 + bc * 1024]);
    }
  };

  stage(0, 0);
  __syncthreads();
  int cur = 0;
  for (int t = 0; t < 24; ++t) {
    if (t < 23) stage(cur ^ 1, (t + 1) * 32);
    const unsigned char* A = smem[cur];
    const unsigned char* B = smem[cur] + 8192;
    bf16x8 af[4], bfr[8];
#pragma unroll
    for (int fm = 0; fm < 4; ++fm)
      af[fm] = *(const bf16x8*)(A + (wm * 64 + fm * 16 + c) * 64 + g * 16);
#pragma unroll
    for (int fn = 0; fn < 8; ++fn)
      bfr[fn] = *(const bf16x8*)(B + (wn * 128 + fn * 16 + c) * 64 + g * 16);
#pragma unroll
    for (int fm = 0; fm < 4; ++fm)
#pragma unroll
      for (int fn = 0; fn < 8; ++fn)
        acc[fm][fn] = mfma_bf16(af[fm], bfr[fn], acc[fm][fn]);
    __syncthreads();
    cur ^= 1;
  }

  // ---- softmax over s (rows of 512) ----
  float* red = (float*)smem;  // [4 wn][128 rows], reused staging space
  float bias[8];
#pragma unroll
  for (int fn = 0; fn < 8; ++fn) bias[fn] = mbias[b * NS + wn * 128 + fn * 16 + c];

  float rmax[4][4];
#pragma unroll
  for (int fm = 0; fm < 4; ++fm)
#pragma unroll
    for (int r = 0; r < 4; ++r) {
      float v = -INFINITY;
#pragma unroll
      for (int fn = 0; fn < 8; ++fn) v = fmaxf(v, acc[fm][fn][r] + bias[fn]);
      v = fmaxf(v, __shfl_xor(v, 1));
      v = fmaxf(v, __shfl_xor(v, 2));
      v = fmaxf(v, __shfl_xor(v, 4));
      v = fmaxf(v, __shfl_xor(v, 8));
      if (c == 0) red[wn * 128 + wm * 64 + fm * 16 + g * 4 + r] = v;
    }
  __syncthreads();
#pragma unroll
  for (int fm = 0; fm < 4; ++fm)
#pragma unroll
    for (int r = 0; r < 4; ++r) {
      int row = wm * 64 + fm * 16 + g * 4 + r;
      rmax[fm][r] = fmaxf(fmaxf(red[row], red[128 + row]),
                          fmaxf(red[256 + row], red[384 + row]));
    }
  __syncthreads();  // everyone done reading maxes before reusing red for sums

  float sums[4][4];
#pragma unroll
  for (int fm = 0; fm < 4; ++fm)
#pragma unroll
    for (int r = 0; r < 4; ++r) {
      float s = 0.f;
#pragma unroll
      for (int fn = 0; fn < 8; ++fn) {
        float p = __expf(acc[fm][fn][r] + bias[fn] - rmax[fm][r]);
        acc[fm][fn][r] = p;
        s += p;
      }
      s += __shfl_xor(s, 1);
      s += __shfl_xor(s, 2);
      s += __shfl_xor(s, 4);
      s += __shfl_xor(s, 8);
      if (c == 0) red[wn * 128 + wm * 64 + fm * 16 + g * 4 + r] = s;
      sums[fm][r] = 0.f;
      (void)sums;
    }
  __syncthreads();

  __bf16* Pb = Pws + ((size_t)b * NL + R0) * NS;
#pragma unroll
  for (int fm = 0; fm < 4; ++fm)
#pragma unroll
    for (int r = 0; r < 4; ++r) {
      int row = wm * 64 + fm * 16 + g * 4 + r;
      float inv = 1.0f / (red[row] + red[128 + row] + red[256 + row] + red[384 + row]);
#pragma unroll
      for (int fn = 0; fn < 8; ++fn)
        Pb[(size_t)row * NS + wn * 128 + fn * 16 + c] = (__bf16)(acc[fm][fn][r] * inv);
    }
}

// ---------------------------------------------------------------------------
// K2: Out = P @ X  (per b). m97-clone: M=NB*NL flat, N=768, K=512, 128x128
// tile, 4 waves (2x2), wave 64x64, BK=32, LDS dbuf 32KB.
// ---------------------------------------------------------------------------
__global__ __launch_bounds__(256, 3) void pv_kernel(
    const __bf16* __restrict__ Pws,   // [NB*NL, NS]
    const __bf16* __restrict__ XTbf,  // [NB, NH, NS]
    float* __restrict__ Out) {        // [NB*NL, NH]
  const int tid = threadIdx.x, lane = tid & 63, wid = tid >> 6;
  const int c = lane & 15, g = lane >> 4;
  const int wm = wid >> 1, wn = wid & 1;
  const int b = blockIdx.z;
  const size_t rowbase = (size_t)b * NL + (size_t)blockIdx.x * 128;
  const int h0 = blockIdx.y * 128;
  __shared__ __align__(16) unsigned char smem[2][16384];
  const __bf16* Xb0 = XTbf + (size_t)b * NH * NS;

  f32x4 acc[4][4];
#pragma unroll
  for (int i = 0; i < 4; ++i)
#pragma unroll
    for (int j = 0; j < 4; ++j) acc[i][j] = (f32x4){0.f, 0.f, 0.f, 0.f};

  auto stage = [&](int buf, int k0) {
#pragma unroll
    for (int it = 0; it < 2; ++it) {
      int ch = it * 4 + wid;              // 0..7
      int idx = ch * 64 + lane;           // 0..511
      int row = idx >> 2, slot = idx & 3;
      llds16(Pws + (rowbase + row) * NS + k0 + slot * 8, &smem[buf][ch * 1024]);
      llds16(Xb0 + (size_t)(h0 + row) * NS + k0 + slot * 8, &smem[buf][8192 + ch * 1024]);
    }
  };

  stage(0, 0);
  __syncthreads();
  int cur = 0;
  for (int t = 0; t < 16; ++t) {
    if (t < 15) stage(cur ^ 1, (t + 1) * 32);
    const unsigned char* A = smem[cur];
    const unsigned char* B = smem[cur] + 8192;
    bf16x8 af[4], bfr[4];
#pragma unroll
    for (int fm = 0; fm < 4; ++fm)
      af[fm] = *(const bf16x8*)(A + (wm * 64 + fm * 16 + c) * 64 + g * 16);
#pragma unroll
    for (int fn = 0; fn < 4; ++fn)
      bfr[fn] = *(const bf16x8*)(B + (wn * 64 + fn * 16 + c) * 64 + g * 16);
#pragma unroll
    for (int fm = 0; fm < 4; ++fm)
#pragma unroll
      for (int fn = 0; fn < 4; ++fn)
        acc[fm][fn] = mfma_bf16(af[fm], bfr[fn], acc[fm][fn]);
    __syncthreads();
    cur ^= 1;
  }
  float* Ob = Out + rowbase * NH;
#pragma unroll
  for (int fm = 0; fm < 4; ++fm)
#pragma unroll
    for (int r = 0; r < 4; ++r) {
      int row = wm * 64 + fm * 16 + g * 4 + r;
#pragma unroll
      for (int fn = 0; fn < 4; ++fn)
        Ob[(size_t)row * NH + h0 + wn * 64 + fn * 16 + c] = acc[fm][fn][r];
    }
}

// ===========================================================================
// Round-1 fallback path (verified passing) — used if ws_size is too small.
// ===========================================================================
__global__ __launch_bounds__(256) void proj_kernel(const float* __restrict__ X,
                                                   const float* __restrict__ W,
                                                   __bf16* __restrict__ Kout) {
  const int tid = threadIdx.x;
  const int lane = tid & 63, wid = tid >> 6;
  const int c = lane & 15, g = lane >> 4;
  const int wm = wid >> 1, wn = wid & 1;
  const int m0 = blockIdx.x * 64 + wm * 32;
  const int n0 = blockIdx.y * 64 + wn * 32;
  f32x4 acc[2][2] = {};
  const float* Xp = X + (size_t)(m0 + c) * NH + g * 8;
  const float* Wp = W + (size_t)(n0 + c) * NH + g * 8;
  for (int k = 0; k < NH; k += 32) {
    bf16x8 a0 = load_cvt8(Xp + k);
    bf16x8 a1 = load_cvt8(Xp + 16 * NH + k);
    bf16x8 b0 = load_cvt8(Wp + k);
    bf16x8 b1 = load_cvt8(Wp + 16 * NH + k);
    acc[0][0] = mfma_bf16(a0, b0, acc[0][0]);
    acc[0][1] = mfma_bf16(a0, b1, acc[0][1]);
    acc[1][0] = mfma_bf16(a1, b0, acc[1][0]);
    acc[1][1] = mfma_bf16(a1, b1, acc[1][1]);
  }
#pragma unroll
  for (int fm = 0; fm < 2; ++fm)
#pragma unroll
    for (int fn = 0; fn < 2; ++fn)
#pragma unroll
      for (int r = 0; r < 4; ++r) {
        int row = m0 + fm * 16 + g * 4 + r;
        int col = n0 + fn * 16 + c;
        Kout[(size_t)row * NH + col] = (__bf16)acc[fm][fn][r];
      }
}

__global__ __launch_bounds__(512) void label_attn_kernel(
    const __bf16* __restrict__ Ebf, const __bf16* __restrict__ Kbf,
    const __bf16* __restrict__ XTbf, const float* __restrict__ mbias,
    float* __restrict__ Out) {
  const int tid = threadIdx.x;
  const int lane = tid & 63, wid = tid >> 6;
  const int c = lane & 15, g = lane >> 4;
  const int wm = wid >> 2, wn = wid & 3;
  const int b = blockIdx.y;
  const int R0 = blockIdx.x * 64;
  __shared__ alignas(16) __bf16 Plds[64 * 512];
  __shared__ float redM[4][64];
  __shared__ float redS[4][64];
  f32x4 acc[2][8];
#pragma unroll
  for (int i = 0; i < 2; ++i)
#pragma unroll
    for (int j = 0; j < 8; ++j) acc[i][j] = (f32x4){0.f, 0.f, 0.f, 0.f};
  const __bf16* Ea = Ebf + (size_t)(R0 + wm * 32 + c) * NH + g * 8;
  const __bf16* Kb = Kbf + ((size_t)b * NS + wn * 128 + c) * NH + g * 8;
  float bias[8];
#pragma unroll
  for (int fn = 0; fn < 8; ++fn) bias[fn] = mbias[b * NS + wn * 128 + fn * 16 + c];
  for (int k = 0; k < NH; k += 32) {
    bf16x8 a0 = *(const bf16x8*)(Ea + k);
    bf16x8 a1 = *(const bf16x8*)(Ea + 16 * NH + k);
#pragma unroll
    for (int fn = 0; fn < 8; ++fn) {
      bf16x8 bb = *(const bf16x8*)(Kb + (size_t)fn * 16 * NH + k);
      acc[0][fn] = mfma_bf16(a0, bb, acc[0][fn]);
      acc[1][fn] = mfma_bf16(a1, bb, acc[1][fn]);
    }
  }
  float pmax[2][4];
#pragma unroll
  for (int fm = 0; fm < 2; ++fm)
#pragma unroll
    for (int r = 0; r < 4; ++r) {
      float v = -INFINITY;
#pragma unroll
      for (int fn = 0; fn < 8; ++fn) v = fmaxf(v, acc[fm][fn][r] + bias[fn]);
#pragma unroll
      for (int off = 1; off < 16; off <<= 1) v = fmaxf(v, __shfl_xor(v, off));
      pmax[fm][r] = v;
    }
  if (c == 0) {
#pragma unroll
    for (int fm = 0; fm < 2; ++fm)
#pragma unroll
      for (int r = 0; r < 4; ++r)
        redM[wn][wm * 32 + fm * 16 + g * 4 + r] = pmax[fm][r];
  }
  __syncthreads();
  float rmax[2][4];
#pragma unroll
  for (int fm = 0; fm < 2; ++fm)
#pragma unroll
    for (int r = 0; r < 4; ++r) {
      int row = wm * 32 + fm * 16 + g * 4 + r;
      rmax[fm][r] = fmaxf(fmaxf(redM[0][row], redM[1][row]),
                          fmaxf(redM[2][row], redM[3][row]));
    }
  float psum[2][4] = {{0.f, 0.f, 0.f, 0.f}, {0.f, 0.f, 0.f, 0.f}};
#pragma unroll
  for (int fm = 0; fm < 2; ++fm)
#pragma unroll
    for (int fn = 0; fn < 8; ++fn) {
      int col = wn * 128 + fn * 16 + c;
#pragma unroll
      for (int r = 0; r < 4; ++r) {
        int row = wm * 32 + fm * 16 + g * 4 + r;
        float p = __expf(acc[fm][fn][r] + bias[fn] - rmax[fm][r]);
        psum[fm][r] += p;
        Plds[row * 512 + (col ^ ((row & 7) << 3))] = (__bf16)p;
      }
    }
#pragma unroll
  for (int fm = 0; fm < 2; ++fm)
#pragma unroll
    for (int r = 0; r < 4; ++r) {
      float v = psum[fm][r];
#pragma unroll
      for (int off = 1; off < 16; off <<= 1) v += __shfl_xor(v, off);
      psum[fm][r] = v;
    }
  if (c == 0) {
#pragma unroll
    for (int fm = 0; fm < 2; ++fm)
#pragma unroll
      for (int r = 0; r < 4; ++r)
        redS[wn][wm * 32 + fm * 16 + g * 4 + r] = psum[fm][r];
  }
  __syncthreads();
  float inv[2][4];
#pragma unroll
  for (int fm = 0; fm < 2; ++fm)
#pragma unroll
    for (int r = 0; r < 4; ++r) {
      int row = wm * 32 + fm * 16 + g * 4 + r;
      float s = redS[0][row] + redS[1][row] + redS[2][row] + redS[3][row];
      inv[fm][r] = 1.0f / s;
    }
  f32x4 acc2[2][12];
#pragma unroll
  for (int i = 0; i < 2; ++i)
#pragma unroll
    for (int j = 0; j < 12; ++j) acc2[i][j] = (f32x4){0.f, 0.f, 0.f, 0.f};
  const __bf16* XTb = XTbf + ((size_t)b * NH + wn * 192 + c) * NS + g * 8;
  const int r0 = wm * 32 + c;
  const int r1 = r0 + 16;
  for (int ks = 0; ks < NS; ks += 32) {
    int kk = ks + g * 8;
    bf16x8 a0 = *(const bf16x8*)&Plds[r0 * 512 + (kk ^ ((r0 & 7) << 3))];
    bf16x8 a1 = *(const bf16x8*)&Plds[r1 * 512 + (kk ^ ((r1 & 7) << 3))];
#pragma unroll
    for (int fn = 0; fn < 12; ++fn) {
      bf16x8 bb = *(const bf16x8*)(XTb + (size_t)fn * 16 * NS + ks);
      acc2[0][fn] = mfma_bf16(a0, bb, acc2[0][fn]);
      acc2[1][fn] = mfma_bf16(a1, bb, acc2[1][fn]);
    }
  }
  float* Ob = Out + ((size_t)b * NL + R0) * NH;
#pragma unroll
  for (int fm = 0; fm < 2; ++fm)
#pragma unroll
    for (int r = 0; r < 4; ++r) {
      int row = wm * 32 + fm * 16 + g * 4 + r;
      float sc = inv[fm][r];
#pragma unroll
      for (int fn = 0; fn < 12; ++fn) {
        int h = wn * 192 + fn * 16 + c;
        Ob[(size_t)row * NH + h] = acc2[fm][fn][r] * sc;
      }
    }
}

// ---------------------------------------------------------------------------
extern "C" void kernel_launch(void* const* d_in, const int* in_sizes, int n_in,
                              void* d_out, int out_size, void* d_ws, size_t ws_size,
                              hipStream_t stream) {
  const float* X = (const float*)d_in[0];   // [8,512,768] f32
  const void* masks = d_in[1];              // [8,1,512] bool (dtype probed)
  const float* E = (const float*)d_in[2];   // [8192,768] f32
  const float* W = (const float*)d_in[3];   // [768,768] f32
  float* Out = (float*)d_out;               // [8,8192,768] f32

  char* ws = (char*)d_ws;
  const size_t NEED = 99762432;

  if (ws_size >= NEED) {
    // ---- staged 3-kernel path ----
    __bf16* Pws  = (__bf16*)ws;                       // 67,108,864
    __bf16* Ebf  = (__bf16*)(ws + 67108864);          // 12,582,912
    __bf16* Kbf  = (__bf16*)(ws + 79691776);          //  6,291,456
    __bf16* XTbf = (__bf16*)(ws + 85983232);          //  6,291,456
    __bf16* Xbf  = (__bf16*)(ws + 92274688);          //  6,291,456
    __bf16* Wbf  = (__bf16*)(ws + 98566144);          //  1,179,648
    float* mbias = (float*)(ws + 99745792);           //     16,384
    int* flag    = (int*)(ws + 99762176);             //          4

    detect_mask_kernel<<<1, 256, 0, stream>>>((const unsigned char*)masks, flag);
    expand_mask_kernel<<<16, 256, 0, stream>>>(masks, flag, mbias);
    cast_kernel<<<1536, 256, 0, stream>>>(X, Xbf);    // 3,145,728 elems
    cast_kernel<<<288, 256, 0, stream>>>(W, Wbf);     //   589,824
    cast_kernel<<<3072, 256, 0, stream>>>(E, Ebf);    // 6,291,456
    transpose_kernel<<<dim3(12, 8, 8), 256, 0, stream>>>(X, XTbf);
    proj_staged_kernel<<<dim3(32, 6), 256, 0, stream>>>(Xbf, Wbf, Kbf);
    scores_kernel<<<dim3(64, 8), 512, 0, stream>>>(Ebf, Kbf, mbias, Pws);
    pv_kernel<<<dim3(64, 6, 8), 256, 0, stream>>>(Pws, XTbf, Out);
  } else {
    // ---- round-1 fallback (25.2 MB ws) ----
    __bf16* Kbf  = (__bf16*)ws;
    __bf16* XTbf = (__bf16*)(ws + 6291456);
    __bf16* Ebf  = (__bf16*)(ws + 12582912);
    float* mbias = (float*)(ws + 25165824);
    int* flag    = (int*)(ws + 25182208);

    detect_mask_kernel<<<1, 256, 0, stream>>>((const unsigned char*)masks, flag);
    expand_mask_kernel<<<16, 256, 0, stream>>>(masks, flag, mbias);
    proj_kernel<<<dim3(64, 12), 256, 0, stream>>>(X, W, Kbf);
    transpose_kernel<<<dim3(12, 8, 8), 256, 0, stream>>>(X, XTbf);
    cast_kernel<<<3072, 256, 0, stream>>>(E, Ebf);
    label_attn_kernel<<<dim3(128, 8), 512, 0, stream>>>(Ebf, Kbf, XTbf, mbias, Out);
  }
}